// Round 3
// baseline (2673.473 us; speedup 1.0000x reference)
//
#include <hip/hip_runtime.h>

#define N_NODES 50000
#define N_EDGES 800000
#define DIM 128
#define EDGE_DIM 16
#define N_LAYERS 3
#define N_GRAPHS 64

// ---------------------------------------------------------------------------
// Edge kernel: per edge e:  m = relu(h[src] + edge_attr@We + be); agg[dst] += m
// One wave (64 lanes) per edge, 2 dims per lane. We columns cached in regs.
// ---------------------------------------------------------------------------
__global__ __launch_bounds__(256) void edge_kernel(
    const float* __restrict__ h,     // [N, 128]
    const float* __restrict__ ea,    // [E, 16]
    const int* __restrict__ src,     // [E]
    const int* __restrict__ dst,     // [E]
    const float* __restrict__ We,    // [16, 128] (this layer)
    const float* __restrict__ be,    // [128]
    float* __restrict__ agg)         // [N, 128], pre-zeroed
{
    const int lane = threadIdx.x & 63;
    const int wave = blockIdx.x * (blockDim.x >> 6) + (threadIdx.x >> 6);
    const int nwaves = gridDim.x * (blockDim.x >> 6);
    const int d0 = 2 * lane;

    // register-cache this lane's two columns of We, plus bias
    float2 w[EDGE_DIM];
#pragma unroll
    for (int k = 0; k < EDGE_DIM; ++k)
        w[k] = *reinterpret_cast<const float2*>(We + k * DIM + d0);
    const float2 bias = *reinterpret_cast<const float2*>(be + d0);

    for (int e = wave; e < N_EDGES; e += nwaves) {
        const int s = src[e];
        const int d = dst[e];
        // broadcast-load the 16 edge features (same addr across lanes -> L1)
        float a[EDGE_DIM];
        const float4* eap = reinterpret_cast<const float4*>(ea + e * EDGE_DIM);
        *reinterpret_cast<float4*>(a + 0)  = eap[0];
        *reinterpret_cast<float4*>(a + 4)  = eap[1];
        *reinterpret_cast<float4*>(a + 8)  = eap[2];
        *reinterpret_cast<float4*>(a + 12) = eap[3];

        float2 acc = bias;
#pragma unroll
        for (int k = 0; k < EDGE_DIM; ++k) {
            acc.x = fmaf(a[k], w[k].x, acc.x);
            acc.y = fmaf(a[k], w[k].y, acc.y);
        }
        const float2 hv = *reinterpret_cast<const float2*>(h + s * DIM + d0);
        const float m0 = fmaxf(hv.x + acc.x, 0.0f);
        const float m1 = fmaxf(hv.y + acc.y, 0.0f);
        atomicAdd(&agg[d * DIM + d0], m0);
        atomicAdd(&agg[d * DIM + d0 + 1], m1);
    }
}

// ---------------------------------------------------------------------------
// Node MLP kernel: h_out = relu( relu((h+agg)@W1+b1) @ W2 + b2 )
// 64 nodes per block, 256 threads, W staged in LDS (32-row k-tiles),
// 8 rows x 4 cols accumulators per thread.
// ---------------------------------------------------------------------------
__global__ __launch_bounds__(256) void node_kernel(
    const float* __restrict__ hin,   // [N,128]
    const float* __restrict__ agg,   // [N,128]
    const float* __restrict__ W1,    // [128,128]
    const float* __restrict__ b1,    // [128]
    const float* __restrict__ W2,    // [128,128]
    const float* __restrict__ b2,    // [128]
    float* __restrict__ hout)        // [N,128]
{
    __shared__ float zt[64 * 128];   // 32 KB: z tile, then t tile
    __shared__ float wt[32 * 128];   // 16 KB: W k-tile

    const int t = threadIdx.x;
    const int n0 = blockIdx.x * 64;
    const int c0 = (t & 31) * 4;
    const int r0 = (t >> 5) * 8;

    // ---- load z tile = hin + agg ----
#pragma unroll
    for (int i = 0; i < 8; ++i) {
        const int f = (i * 256 + t) * 4;         // float idx in tile [0,8192)
        const int node = n0 + (f >> 7);
        const int dim = f & 127;
        float4 v = make_float4(0.f, 0.f, 0.f, 0.f);
        if (node < N_NODES) {
            const float4 hv = *reinterpret_cast<const float4*>(hin + node * DIM + dim);
            const float4 av = *reinterpret_cast<const float4*>(agg + node * DIM + dim);
            v = make_float4(hv.x + av.x, hv.y + av.y, hv.z + av.z, hv.w + av.w);
        }
        *reinterpret_cast<float4*>(&zt[f]) = v;
    }

    const float4 bb1 = *reinterpret_cast<const float4*>(b1 + c0);
    const float4 bb2 = *reinterpret_cast<const float4*>(b2 + c0);

    float acc[8][4];
#pragma unroll
    for (int i = 0; i < 8; ++i)
#pragma unroll
        for (int j = 0; j < 4; ++j) acc[i][j] = 0.0f;

    // ---- stage 1: t = relu(z @ W1 + b1) ----
    for (int kk = 0; kk < 4; ++kk) {
        __syncthreads();                         // zt loaded / wt free
#pragma unroll
        for (int i = 0; i < 4; ++i) {
            const int f = (i * 256 + t) * 4;     // [0,4096)
            *reinterpret_cast<float4*>(&wt[f]) =
                *reinterpret_cast<const float4*>(W1 + kk * 32 * 128 + f);
        }
        __syncthreads();
#pragma unroll
        for (int k = 0; k < 32; ++k) {
            const float4 wv = *reinterpret_cast<const float4*>(&wt[k * 128 + c0]);
#pragma unroll
            for (int i = 0; i < 8; ++i) {
                const float zv = zt[(r0 + i) * 128 + kk * 32 + k];
                acc[i][0] = fmaf(zv, wv.x, acc[i][0]);
                acc[i][1] = fmaf(zv, wv.y, acc[i][1]);
                acc[i][2] = fmaf(zv, wv.z, acc[i][2]);
                acc[i][3] = fmaf(zv, wv.w, acc[i][3]);
            }
        }
    }
    __syncthreads();                             // all stage-1 reads done
    // write t into zt, reset acc
#pragma unroll
    for (int i = 0; i < 8; ++i) {
        float4 v = make_float4(fmaxf(acc[i][0] + bb1.x, 0.f),
                               fmaxf(acc[i][1] + bb1.y, 0.f),
                               fmaxf(acc[i][2] + bb1.z, 0.f),
                               fmaxf(acc[i][3] + bb1.w, 0.f));
        *reinterpret_cast<float4*>(&zt[(r0 + i) * 128 + c0]) = v;
#pragma unroll
        for (int j = 0; j < 4; ++j) acc[i][j] = 0.0f;
    }

    // ---- stage 2: h = relu(t @ W2 + b2) ----
    for (int kk = 0; kk < 4; ++kk) {
        __syncthreads();
#pragma unroll
        for (int i = 0; i < 4; ++i) {
            const int f = (i * 256 + t) * 4;
            *reinterpret_cast<float4*>(&wt[f]) =
                *reinterpret_cast<const float4*>(W2 + kk * 32 * 128 + f);
        }
        __syncthreads();
#pragma unroll
        for (int k = 0; k < 32; ++k) {
            const float4 wv = *reinterpret_cast<const float4*>(&wt[k * 128 + c0]);
#pragma unroll
            for (int i = 0; i < 8; ++i) {
                const float zv = zt[(r0 + i) * 128 + kk * 32 + k];
                acc[i][0] = fmaf(zv, wv.x, acc[i][0]);
                acc[i][1] = fmaf(zv, wv.y, acc[i][1]);
                acc[i][2] = fmaf(zv, wv.z, acc[i][2]);
                acc[i][3] = fmaf(zv, wv.w, acc[i][3]);
            }
        }
    }

    // ---- epilogue ----
#pragma unroll
    for (int i = 0; i < 8; ++i) {
        const int node = n0 + r0 + i;
        if (node < N_NODES) {
            float4 v = make_float4(fmaxf(acc[i][0] + bb2.x, 0.f),
                                   fmaxf(acc[i][1] + bb2.y, 0.f),
                                   fmaxf(acc[i][2] + bb2.z, 0.f),
                                   fmaxf(acc[i][3] + bb2.w, 0.f));
            *reinterpret_cast<float4*>(hout + node * DIM + c0) = v;
        }
    }
}

// ---------------------------------------------------------------------------
// Pool: g_sum[batch[n]] += h[n]; cnt[batch[n]] += 1.  One wave per node.
// ---------------------------------------------------------------------------
__global__ __launch_bounds__(256) void pool_kernel(
    const float* __restrict__ h, const int* __restrict__ batch,
    float* __restrict__ gsum, float* __restrict__ cnt)
{
    const int lane = threadIdx.x & 63;
    const int wave = blockIdx.x * (blockDim.x >> 6) + (threadIdx.x >> 6);
    const int nwaves = gridDim.x * (blockDim.x >> 6);
    const int d0 = 2 * lane;
    for (int n = wave; n < N_NODES; n += nwaves) {
        const int b = batch[n];
        const float2 hv = *reinterpret_cast<const float2*>(h + n * DIM + d0);
        atomicAdd(&gsum[b * DIM + d0], hv.x);
        atomicAdd(&gsum[b * DIM + d0 + 1], hv.y);
        if (lane == 0) atomicAdd(&cnt[b], 1.0f);
    }
}

// ---------------------------------------------------------------------------
// Readout: out[g] = relu(mean_g @ Wh1 + bh1) @ Wh2 + bh2.  64 blocks x 128 thr.
// ---------------------------------------------------------------------------
__global__ __launch_bounds__(128) void readout_kernel(
    const float* __restrict__ gsum, const float* __restrict__ cnt,
    const float* __restrict__ Wh1, const float* __restrict__ bh1,
    const float* __restrict__ Wh2, const float* __restrict__ bh2,
    float* __restrict__ out)
{
    __shared__ float gv[128];
    __shared__ float partial[2];
    const int g = blockIdx.x;
    const int t = threadIdx.x;
    const float c = fmaxf(cnt[g], 1.0f);
    gv[t] = gsum[g * DIM + t] / c;
    __syncthreads();
    float acc = bh1[t];
    for (int k = 0; k < DIM; ++k)
        acc = fmaf(gv[k], Wh1[k * DIM + t], acc);
    float tv = fmaxf(acc, 0.0f) * Wh2[t];
    // reduce 128 values (2 waves)
    for (int off = 32; off > 0; off >>= 1) tv += __shfl_down(tv, off);
    if ((t & 63) == 0) partial[t >> 6] = tv;
    __syncthreads();
    if (t == 0) out[g] = partial[0] + partial[1] + bh2[0];
}

// ---------------------------------------------------------------------------
extern "C" void kernel_launch(void* const* d_in, const int* in_sizes, int n_in,
                              void* d_out, int out_size, void* d_ws, size_t ws_size,
                              hipStream_t stream) {
    const float* x         = (const float*)d_in[0];
    const int*   edge_idx  = (const int*)d_in[1];
    const int*   batch     = (const int*)d_in[2];
    const float* edge_attr = (const float*)d_in[3];
    const float* W1        = (const float*)d_in[4];
    const float* b1        = (const float*)d_in[5];
    const float* W2        = (const float*)d_in[6];
    const float* b2        = (const float*)d_in[7];
    const float* We        = (const float*)d_in[8];
    const float* be        = (const float*)d_in[9];
    const float* Wh1       = (const float*)d_in[10];
    const float* bh1       = (const float*)d_in[11];
    const float* Wh2       = (const float*)d_in[12];
    const float* bh2       = (const float*)d_in[13];
    float* out = (float*)d_out;

    const int* src = edge_idx;            // edge_index[0]
    const int* dst = edge_idx + N_EDGES;  // edge_index[1]

    float* ws = (float*)d_ws;
    float* h_ws = ws;                                  // 50000*128
    float* agg  = ws + (size_t)N_NODES * DIM;          // 50000*128
    float* gsum = agg + (size_t)N_NODES * DIM;         // 64*128
    float* cntf = gsum + (size_t)N_GRAPHS * DIM;       // 64

    const size_t agg_bytes = (size_t)N_NODES * DIM * sizeof(float);

    const float* hin = x;
    for (int l = 0; l < N_LAYERS; ++l) {
        hipMemsetAsync(agg, 0, agg_bytes, stream);
        edge_kernel<<<4096, 256, 0, stream>>>(
            hin, edge_attr, src, dst,
            We + (size_t)l * EDGE_DIM * DIM, be + (size_t)l * DIM, agg);
        node_kernel<<<(N_NODES + 63) / 64, 256, 0, stream>>>(
            hin, agg,
            W1 + (size_t)l * DIM * DIM, b1 + (size_t)l * DIM,
            W2 + (size_t)l * DIM * DIM, b2 + (size_t)l * DIM,
            h_ws);
        hin = h_ws;
    }

    hipMemsetAsync(gsum, 0, ((size_t)N_GRAPHS * DIM + N_GRAPHS) * sizeof(float), stream);
    pool_kernel<<<1024, 256, 0, stream>>>(h_ws, batch, gsum, cntf);
    readout_kernel<<<N_GRAPHS, 128, 0, stream>>>(gsum, cntf, Wh1, bh1, Wh2, bh2, out);
}

// Round 4
// 960.429 us; speedup vs baseline: 2.7836x; 2.7836x over previous
//
#include <hip/hip_runtime.h>

#define N_NODES 50000
#define N_EDGES 800000
#define DIM 128
#define EDGE_DIM 16
#define N_LAYERS 3
#define N_GRAPHS 64

// ---------------------------------------------------------------------------
// CSR build: histogram of dst -> exclusive scan -> scatter edge ids.
// After scatter, row_ptr[n] = start[n] + deg[n] = start[n+1]; gather uses
// beg = (n==0)?0:row_ptr[n-1], end = row_ptr[n].
// ---------------------------------------------------------------------------
__global__ __launch_bounds__(256) void hist_kernel(
    const int* __restrict__ dst, int* __restrict__ row_ptr)
{
    const int e = blockIdx.x * 256 + threadIdx.x;
    if (e < N_EDGES) atomicAdd(&row_ptr[dst[e]], 1);
}

__global__ __launch_bounds__(1024) void scan_kernel(int* __restrict__ rp)
{
    __shared__ int sums[1024];
    const int t = threadIdx.x;
    const int chunk = (N_NODES + 1023) / 1024;   // 49
    const int lo = t * chunk;
    const int hi = min(lo + chunk, N_NODES);
    int s = 0;
    for (int j = lo; j < hi; ++j) s += rp[j];
    sums[t] = s;
    __syncthreads();
    // Hillis-Steele inclusive scan over 1024 partials
    for (int off = 1; off < 1024; off <<= 1) {
        int v = (t >= off) ? sums[t - off] : 0;
        __syncthreads();
        sums[t] += v;
        __syncthreads();
    }
    int run = (t == 0) ? 0 : sums[t - 1];        // exclusive prefix
    for (int j = lo; j < hi; ++j) {
        const int v = rp[j];
        rp[j] = run;
        run += v;
    }
    if (t == 1023) rp[N_NODES] = run;
}

__global__ __launch_bounds__(256) void scatter_kernel(
    const int* __restrict__ dst, int* __restrict__ row_ptr,
    int* __restrict__ eids)
{
    const int e = blockIdx.x * 256 + threadIdx.x;
    if (e < N_EDGES) {
        const int pos = atomicAdd(&row_ptr[dst[e]], 1);
        eids[pos] = e;
    }
}

// ---------------------------------------------------------------------------
// Gather kernel (atomic-free aggregation). One wave per node, 2 dims/lane.
// z[n] = h[n] + sum_{e in in(n)} relu(h[src[e]] + ea[e]@We + be)
// We columns register-cached (32 VGPRs).
// ---------------------------------------------------------------------------
__global__ __launch_bounds__(256) void gather_kernel(
    const float* __restrict__ h,     // [N,128]
    const float* __restrict__ ea,    // [E,16]
    const int* __restrict__ src,     // [E]
    const int* __restrict__ eids,    // [E] CSR-ordered edge ids
    const int* __restrict__ row_end, // [N] end pointers (see build)
    const float* __restrict__ We,    // [16,128]
    const float* __restrict__ be,    // [128]
    float* __restrict__ z)           // [N,128]
{
    const int lane = threadIdx.x & 63;
    const int n = blockIdx.x * (blockDim.x >> 6) + (threadIdx.x >> 6);
    if (n >= N_NODES) return;
    const int d0 = 2 * lane;

    float2 w[EDGE_DIM];
#pragma unroll
    for (int k = 0; k < EDGE_DIM; ++k)
        w[k] = *reinterpret_cast<const float2*>(We + k * DIM + d0);
    const float2 bias = *reinterpret_cast<const float2*>(be + d0);

    const int beg = (n == 0) ? 0 : row_end[n - 1];
    const int end = row_end[n];

    float2 acc = *reinterpret_cast<const float2*>(h + (size_t)n * DIM + d0);

    for (int idx = beg; idx < end; ++idx) {
        const int e = eids[idx];
        const int s = src[e];
        const float4* eap = reinterpret_cast<const float4*>(ea + (size_t)e * EDGE_DIM);
        float2 t = bias;
#pragma unroll
        for (int q = 0; q < 4; ++q) {
            const float4 a = eap[q];
            t.x = fmaf(a.x, w[4*q+0].x, t.x); t.y = fmaf(a.x, w[4*q+0].y, t.y);
            t.x = fmaf(a.y, w[4*q+1].x, t.x); t.y = fmaf(a.y, w[4*q+1].y, t.y);
            t.x = fmaf(a.z, w[4*q+2].x, t.x); t.y = fmaf(a.z, w[4*q+2].y, t.y);
            t.x = fmaf(a.w, w[4*q+3].x, t.x); t.y = fmaf(a.w, w[4*q+3].y, t.y);
        }
        const float2 hs = *reinterpret_cast<const float2*>(h + (size_t)s * DIM + d0);
        acc.x += fmaxf(hs.x + t.x, 0.0f);
        acc.y += fmaxf(hs.y + t.y, 0.0f);
    }
    *reinterpret_cast<float2*>(z + (size_t)n * DIM + d0) = acc;
}

// ---------------------------------------------------------------------------
// Node MLP kernel: h_out = relu( relu(z@W1+b1) @ W2 + b2 )
// 64 nodes per block, 256 threads, W staged in LDS (32-row k-tiles),
// 8 rows x 4 cols accumulators per thread.
// ---------------------------------------------------------------------------
__global__ __launch_bounds__(256) void node_kernel(
    const float* __restrict__ zin,   // [N,128] (already h+agg)
    const float* __restrict__ W1,    // [128,128]
    const float* __restrict__ b1,    // [128]
    const float* __restrict__ W2,    // [128,128]
    const float* __restrict__ b2,    // [128]
    float* __restrict__ hout)        // [N,128]
{
    __shared__ float zt[64 * 128];   // 32 KB: z tile, then t tile
    __shared__ float wt[32 * 128];   // 16 KB: W k-tile

    const int t = threadIdx.x;
    const int n0 = blockIdx.x * 64;
    const int c0 = (t & 31) * 4;
    const int r0 = (t >> 5) * 8;

    // ---- load z tile ----
#pragma unroll
    for (int i = 0; i < 8; ++i) {
        const int f = (i * 256 + t) * 4;         // float idx in tile [0,8192)
        const int node = n0 + (f >> 7);
        const int dim = f & 127;
        float4 v = make_float4(0.f, 0.f, 0.f, 0.f);
        if (node < N_NODES)
            v = *reinterpret_cast<const float4*>(zin + (size_t)node * DIM + dim);
        *reinterpret_cast<float4*>(&zt[f]) = v;
    }

    const float4 bb1 = *reinterpret_cast<const float4*>(b1 + c0);
    const float4 bb2 = *reinterpret_cast<const float4*>(b2 + c0);

    float acc[8][4];
#pragma unroll
    for (int i = 0; i < 8; ++i)
#pragma unroll
        for (int j = 0; j < 4; ++j) acc[i][j] = 0.0f;

    // ---- stage 1: t = relu(z @ W1 + b1) ----
    for (int kk = 0; kk < 4; ++kk) {
        __syncthreads();
#pragma unroll
        for (int i = 0; i < 4; ++i) {
            const int f = (i * 256 + t) * 4;
            *reinterpret_cast<float4*>(&wt[f]) =
                *reinterpret_cast<const float4*>(W1 + kk * 32 * 128 + f);
        }
        __syncthreads();
#pragma unroll
        for (int k = 0; k < 32; ++k) {
            const float4 wv = *reinterpret_cast<const float4*>(&wt[k * 128 + c0]);
#pragma unroll
            for (int i = 0; i < 8; ++i) {
                const float zv = zt[(r0 + i) * 128 + kk * 32 + k];
                acc[i][0] = fmaf(zv, wv.x, acc[i][0]);
                acc[i][1] = fmaf(zv, wv.y, acc[i][1]);
                acc[i][2] = fmaf(zv, wv.z, acc[i][2]);
                acc[i][3] = fmaf(zv, wv.w, acc[i][3]);
            }
        }
    }
    __syncthreads();
    // write t into zt, reset acc
#pragma unroll
    for (int i = 0; i < 8; ++i) {
        float4 v = make_float4(fmaxf(acc[i][0] + bb1.x, 0.f),
                               fmaxf(acc[i][1] + bb1.y, 0.f),
                               fmaxf(acc[i][2] + bb1.z, 0.f),
                               fmaxf(acc[i][3] + bb1.w, 0.f));
        *reinterpret_cast<float4*>(&zt[(r0 + i) * 128 + c0]) = v;
#pragma unroll
        for (int j = 0; j < 4; ++j) acc[i][j] = 0.0f;
    }

    // ---- stage 2: h = relu(t @ W2 + b2) ----
    for (int kk = 0; kk < 4; ++kk) {
        __syncthreads();
#pragma unroll
        for (int i = 0; i < 4; ++i) {
            const int f = (i * 256 + t) * 4;
            *reinterpret_cast<float4*>(&wt[f]) =
                *reinterpret_cast<const float4*>(W2 + kk * 32 * 128 + f);
        }
        __syncthreads();
#pragma unroll
        for (int k = 0; k < 32; ++k) {
            const float4 wv = *reinterpret_cast<const float4*>(&wt[k * 128 + c0]);
#pragma unroll
            for (int i = 0; i < 8; ++i) {
                const float zv = zt[(r0 + i) * 128 + kk * 32 + k];
                acc[i][0] = fmaf(zv, wv.x, acc[i][0]);
                acc[i][1] = fmaf(zv, wv.y, acc[i][1]);
                acc[i][2] = fmaf(zv, wv.z, acc[i][2]);
                acc[i][3] = fmaf(zv, wv.w, acc[i][3]);
            }
        }
    }

    // ---- epilogue ----
#pragma unroll
    for (int i = 0; i < 8; ++i) {
        const int node = n0 + r0 + i;
        if (node < N_NODES) {
            float4 v = make_float4(fmaxf(acc[i][0] + bb2.x, 0.f),
                                   fmaxf(acc[i][1] + bb2.y, 0.f),
                                   fmaxf(acc[i][2] + bb2.z, 0.f),
                                   fmaxf(acc[i][3] + bb2.w, 0.f));
            *reinterpret_cast<float4*>(hout + (size_t)node * DIM + c0) = v;
        }
    }
}

// ---------------------------------------------------------------------------
// Pool: batch is SORTED -> run-length accumulate per wave, flush one atomic
// set per graph-run. Wave owns 64 contiguous nodes, 2 dims/lane.
// ---------------------------------------------------------------------------
__global__ __launch_bounds__(256) void pool_kernel(
    const float* __restrict__ h, const int* __restrict__ batch,
    float* __restrict__ gsum, float* __restrict__ cnt)
{
    const int lane = threadIdx.x & 63;
    const int wave = blockIdx.x * (blockDim.x >> 6) + (threadIdx.x >> 6);
    const int n0 = wave * 64;
    if (n0 >= N_NODES) return;
    const int n1 = min(n0 + 64, N_NODES);
    const int d0 = 2 * lane;

    int gcur = batch[n0];
    float2 acc = make_float2(0.f, 0.f);
    float c = 0.f;
    for (int n = n0; n < n1; ++n) {
        const int b = batch[n];
        if (b != gcur) {
            atomicAdd(&gsum[gcur * DIM + d0], acc.x);
            atomicAdd(&gsum[gcur * DIM + d0 + 1], acc.y);
            if (lane == 0) atomicAdd(&cnt[gcur], c);
            gcur = b; acc = make_float2(0.f, 0.f); c = 0.f;
        }
        const float2 hv = *reinterpret_cast<const float2*>(h + (size_t)n * DIM + d0);
        acc.x += hv.x; acc.y += hv.y; c += 1.f;
    }
    atomicAdd(&gsum[gcur * DIM + d0], acc.x);
    atomicAdd(&gsum[gcur * DIM + d0 + 1], acc.y);
    if (lane == 0) atomicAdd(&cnt[gcur], c);
}

// ---------------------------------------------------------------------------
// Readout: out[g] = relu(mean_g @ Wh1 + bh1) @ Wh2 + bh2.
// ---------------------------------------------------------------------------
__global__ __launch_bounds__(128) void readout_kernel(
    const float* __restrict__ gsum, const float* __restrict__ cnt,
    const float* __restrict__ Wh1, const float* __restrict__ bh1,
    const float* __restrict__ Wh2, const float* __restrict__ bh2,
    float* __restrict__ out)
{
    __shared__ float gv[128];
    __shared__ float partial[2];
    const int g = blockIdx.x;
    const int t = threadIdx.x;
    const float c = fmaxf(cnt[g], 1.0f);
    gv[t] = gsum[g * DIM + t] / c;
    __syncthreads();
    float acc = bh1[t];
    for (int k = 0; k < DIM; ++k)
        acc = fmaf(gv[k], Wh1[k * DIM + t], acc);
    float tv = fmaxf(acc, 0.0f) * Wh2[t];
    for (int off = 32; off > 0; off >>= 1) tv += __shfl_down(tv, off);
    if ((t & 63) == 0) partial[t >> 6] = tv;
    __syncthreads();
    if (t == 0) out[g] = partial[0] + partial[1] + bh2[0];
}

// ---------------------------------------------------------------------------
extern "C" void kernel_launch(void* const* d_in, const int* in_sizes, int n_in,
                              void* d_out, int out_size, void* d_ws, size_t ws_size,
                              hipStream_t stream) {
    const float* x         = (const float*)d_in[0];
    const int*   edge_idx  = (const int*)d_in[1];
    const int*   batch     = (const int*)d_in[2];
    const float* edge_attr = (const float*)d_in[3];
    const float* W1        = (const float*)d_in[4];
    const float* b1        = (const float*)d_in[5];
    const float* W2        = (const float*)d_in[6];
    const float* b2        = (const float*)d_in[7];
    const float* We        = (const float*)d_in[8];
    const float* be        = (const float*)d_in[9];
    const float* Wh1       = (const float*)d_in[10];
    const float* bh1       = (const float*)d_in[11];
    const float* Wh2       = (const float*)d_in[12];
    const float* bh2       = (const float*)d_in[13];
    float* out = (float*)d_out;

    const int* src = edge_idx;            // edge_index[0]
    const int* dst = edge_idx + N_EDGES;  // edge_index[1]

    float* ws = (float*)d_ws;
    float* h_ws   = ws;                                   // 50000*128 f
    float* z_ws   = h_ws + (size_t)N_NODES * DIM;         // 50000*128 f
    float* gsum   = z_ws + (size_t)N_NODES * DIM;         // 64*128 f
    float* cntf   = gsum + (size_t)N_GRAPHS * DIM;        // 64 f
    int*   row_ptr = (int*)(cntf + N_GRAPHS);             // 50001 i
    int*   eids    = row_ptr + (N_NODES + 1);             // 800000 i

    // ---- CSR build (once per launch; reused by all 3 layers) ----
    hipMemsetAsync(row_ptr, 0, (N_NODES + 1) * sizeof(int), stream);
    hist_kernel<<<(N_EDGES + 255) / 256, 256, 0, stream>>>(dst, row_ptr);
    scan_kernel<<<1, 1024, 0, stream>>>(row_ptr);
    scatter_kernel<<<(N_EDGES + 255) / 256, 256, 0, stream>>>(dst, row_ptr, eids);

    // ---- layers ----
    const float* hin = x;
    for (int l = 0; l < N_LAYERS; ++l) {
        gather_kernel<<<(N_NODES + 3) / 4, 256, 0, stream>>>(
            hin, edge_attr, src, eids, row_ptr,
            We + (size_t)l * EDGE_DIM * DIM, be + (size_t)l * DIM, z_ws);
        node_kernel<<<(N_NODES + 63) / 64, 256, 0, stream>>>(
            z_ws,
            W1 + (size_t)l * DIM * DIM, b1 + (size_t)l * DIM,
            W2 + (size_t)l * DIM * DIM, b2 + (size_t)l * DIM,
            h_ws);
        hin = h_ws;
    }

    // ---- pool + readout ----
    hipMemsetAsync(gsum, 0, ((size_t)N_GRAPHS * DIM + N_GRAPHS) * sizeof(float), stream);
    pool_kernel<<<(N_NODES + 64 * 4 - 1) / (64 * 4), 256, 0, stream>>>(h_ws, batch, gsum, cntf);
    readout_kernel<<<N_GRAPHS, 128, 0, stream>>>(gsum, cntf, Wh1, bh1, Wh2, bh2, out);
}